// Round 20
// baseline (35.752 us; speedup 1.0000x reference)
//
#include <hip/hip_runtime.h>
#include <hip/hip_bf16.h>
#include <stdint.h>

// B=4, C=256, H=W=64 -> L=4096, POS=16384; n_mem=64, sqrt_fin=16, scale=1/4.
using bf16 = __hip_bfloat16;
typedef __attribute__((ext_vector_type(8))) short bf16x8;
typedef __attribute__((ext_vector_type(4))) float f32x4;

#define CDIM 256
#define LDIM 4096

// LDS map (140 KiB), 64 pos/block, 256 blocks, 512 threads, 1 block/CU:
// xres @0      : [256 c][68 f32] padded residual tile (69632 B) -- persists to end
// Xs   @69632  : [64 p][256 k] bf16 swizzled (32 KB) -- dead after a_cache;
//                QSW [64p][16s][8w] bf16 overlays here after Q loop (16 KB)
// pooled @102400 : [64 p][64 n] bf16 swizzled (8 KB)
// Mlds @110592 : [256 o2][64 n] bf16 swizzled (32 KB), staged at join
#define XRES_OFF 0
#define XS_OFF 69632
#define POOL_OFF 102400
#define MLDS_OFF 110592

__device__ __forceinline__ void gload16(void* lds, const void* g) {
  auto* l3 = (__attribute__((address_space(3))) char*)(uintptr_t)lds;
  auto* g1 = (const __attribute__((address_space(1))) char*)(uintptr_t)g;
  __builtin_amdgcn_global_load_lds((const __attribute__((address_space(1))) void*)g1,
                                   (__attribute__((address_space(3))) void*)l3, 16, 0, 0);
}

template <int CTRL>
__device__ __forceinline__ float dpp_add(float v) {
  int p = __builtin_amdgcn_update_dpp(0, __float_as_int(v), CTRL, 0xf, 0xf, true);
  return v + __int_as_float(p);
}

__device__ __forceinline__ float b2f(short h) {
  return __uint_as_float(((uint32_t)(uint16_t)h) << 16);
}

// ---------- prep: weights -> bf16 FRAGMENT-ORDER tiles + MmB ----------
__global__ void prep_kernel(const float* __restrict__ Wq, const float* __restrict__ Wk,
                            const float* __restrict__ v, const float* __restrict__ Wo,
                            bf16* __restrict__ Wqt, bf16* __restrict__ Wkt,
                            bf16* __restrict__ MmBg) {
  int bid = blockIdx.x, t = threadIdx.x;
  if (bid < 256) {
    const float* src = (bid < 128) ? Wq : Wk;
    bf16* dst = (bid < 128) ? Wqt : Wkt;
    int f = (bid & 127) * 256 + t;  // 0..32767
    int l = f & 63, kt = (f >> 6) & 7, c2 = f >> 9;
    int row = c2 * 16 + (l & 15);
    int col0 = kt * 32 + (l >> 4) * 8;
    const float* sp = src + row * CDIM + col0;
    float4 fa = *(const float4*)sp;
    float4 fb = *(const float4*)(sp + 4);
    bf16 hv[8];
    hv[0] = __float2bfloat16(fa.x); hv[1] = __float2bfloat16(fa.y);
    hv[2] = __float2bfloat16(fa.z); hv[3] = __float2bfloat16(fa.w);
    hv[4] = __float2bfloat16(fb.x); hv[5] = __float2bfloat16(fb.y);
    hv[6] = __float2bfloat16(fb.z); hv[7] = __float2bfloat16(fb.w);
    *(uint4*)((char*)dst + (size_t)f * 16) = *(const uint4*)hv;
  } else {
    __shared__ float red[256];
    int o = bid - 256;
    int n = t >> 2, cg = t & 3;
    const float* vr = v + n * CDIM + cg * 64;
    const float* wr = Wo + o * CDIM + cg * 64;
    float a = 0.f;
    for (int c = 0; c < 64; c++) a += vr[c] * wr[c];
    red[t] = a;
    __syncthreads();
    if (t < 64)
      MmBg[o * 64 + t] =
          __float2bfloat16(red[t * 4] + red[t * 4 + 1] + red[t * 4 + 2] + red[t * 4 + 3]);
  }
}

__global__ __launch_bounds__(512, 1) void fused_kernel(
    const float* __restrict__ x, const bf16* __restrict__ Wqt, const bf16* __restrict__ Wkt,
    const float* __restrict__ bq, const float* __restrict__ bk,
    const bf16* __restrict__ MmBg, const float* __restrict__ bo, float* __restrict__ out) {
  __shared__ __align__(16) char smem[143360];
  const int tid = threadIdx.x;
  const int w = tid >> 6, lane = tid & 63;
  const int s = lane & 15, g4 = lane >> 4;
  const int pos0 = blockIdx.x * 64;
  const int bb = pos0 >> 12, l0 = pos0 & (LDIM - 1);
  // chunk-phase rotation: same-XCD blocks (bid%8 fixed) get different phases
  const int R = (blockIdx.x >> 3) & 7;
  const int wr = (w + R) & 7;

  // ---- bias hoist, indexed by ITERATION (iteration c handles chunk wr*8+((c+R)&7)) ----
  float bqr[8], bkr[8];
#pragma unroll
  for (int c = 0; c < 8; c++) {
    int ch = wr * 8 + ((c + R) & 7);
    bqr[c] = bq[ch * 16 + s];
    bkr[c] = bk[ch * 16 + s];
  }

  // ---- X stage: x [C][L] f32 -> Xs bf16 swizzled + xres f32 padded; NT loads ----
#pragma unroll
  for (int j = 0; j < 8; j++) {
    int slot = j * 512 + tid;  // 4096 float4 slots = 256 k x 16 (p/4)
    int k = slot >> 4, p0 = (slot & 15) * 4;
    f32x4 f = __builtin_nontemporal_load(
        (const f32x4*)(x + ((size_t)bb * CDIM + k) * LDIM + l0 + p0));
    *(f32x4*)(smem + XRES_OFF + (size_t)(k * 68 + p0) * 4) = f;  // residual copy
#pragma unroll
    for (int jj = 0; jj < 4; jj++) {
      int p = p0 + jj;
      *(bf16*)(smem + XS_OFF + p * 512 + (((k >> 3) ^ (p & 7)) << 4) + (k & 7) * 2) =
          __float2bfloat16(f[jj]);
    }
  }
  __syncthreads();

  // ---- A fragments -> registers/AGPRs: 32 x bf16x8 ----
  bf16x8 a_cache[4][8];
#pragma unroll
  for (int mf = 0; mf < 4; mf++) {
    int arow = mf * 16 + s;
#pragma unroll
    for (int kt = 0; kt < 8; kt++)
      a_cache[mf][kt] =
          *(const bf16x8*)(smem + XS_OFF + arow * 512 + (((kt * 4 + g4) ^ (arow & 7)) << 4));
  }

  // ================= Q projection: 8 chunks (rotated), FULL UNROLL, no setprio —
  // nothing blocks the scheduler from hoisting next-chunk loads over MFMAs =================
  float qacc[4][4] = {};
#pragma unroll
  for (int c = 0; c < 8; c++) {
    int ch = wr * 8 + ((c + R) & 7);
    const char* base = (const char*)Wqt + (size_t)ch * 8192 + lane * 16;
    bf16x8 wf[8];
#pragma unroll
    for (int kt = 0; kt < 8; kt++) wf[kt] = *(const bf16x8*)(base + kt * 1024);
    f32x4 acc[4] = {};
#pragma unroll
    for (int kt = 0; kt < 8; kt++)
#pragma unroll
      for (int mf = 0; mf < 4; mf++)
        acc[mf] = __builtin_amdgcn_mfma_f32_16x16x32_bf16(a_cache[mf][kt], wf[kt], acc[mf], 0, 0, 0);
#pragma unroll
    for (int mf = 0; mf < 4; mf++)
#pragma unroll
      for (int r = 0; r < 4; r++) qacc[mf][r] += fmaxf(acc[mf][r] + bqr[c], 0.f);
  }

  // ---- merge qsum across 8 waves via bf16 LDS (QSW overlays dead Xs) ----
#pragma unroll
  for (int mf = 0; mf < 4; mf++)
#pragma unroll
    for (int r = 0; r < 4; r++) {
      int pos_l = mf * 16 + g4 * 4 + r;
      *(bf16*)(smem + XS_OFF + ((pos_l * 16 + s) * 8 + w) * 2) = __float2bfloat16(qacc[mf][r]);
    }
  __syncthreads();
  float qreg[4][4];
#pragma unroll
  for (int mf = 0; mf < 4; mf++)
#pragma unroll
    for (int r = 0; r < 4; r++) {
      int pos_l = mf * 16 + g4 * 4 + r;
      bf16x8 vv = *(const bf16x8*)(smem + XS_OFF + (pos_l * 16 + s) * 16);
      float sum = 0.f;
#pragma unroll
      for (int j = 0; j < 8; j++) sum += b2f(vv[j]);
      qreg[mf][r] = 0.00390625f * sum;  // (1/4)/64
    }

  // ================= K projection: 8 chunks (rotated), FULL UNROLL, no setprio =================
#pragma unroll
  for (int c = 0; c < 8; c++) {
    int ch = wr * 8 + ((c + R) & 7);
    const char* base = (const char*)Wkt + (size_t)ch * 8192 + lane * 16;
    bf16x8 wf[8];
#pragma unroll
    for (int kt = 0; kt < 8; kt++) wf[kt] = *(const bf16x8*)(base + kt * 1024);
    f32x4 acc[4] = {};
#pragma unroll
    for (int kt = 0; kt < 8; kt++)
#pragma unroll
      for (int mf = 0; mf < 4; mf++)
        acc[mf] = __builtin_amdgcn_mfma_f32_16x16x32_bf16(a_cache[mf][kt], wf[kt], acc[mf], 0, 0, 0);
    float red[16];
#pragma unroll
    for (int mf = 0; mf < 4; mf++)
#pragma unroll
      for (int r = 0; r < 4; r++) {
        float tt = qreg[mf][r] * fmaxf(acc[mf][r] + bkr[c], 0.f);
        tt = dpp_add<0x128>(tt);  // row_ror:8
        tt = dpp_add<0x124>(tt);  // row_ror:4
        tt = dpp_add<0x122>(tt);  // row_ror:2
        tt = dpp_add<0x121>(tt);  // row_ror:1
        red[mf * 4 + r] = tt;     // sum over 16 s-lanes, in all lanes
      }
    float a0 = (s & 1) ? red[1] : red[0];
    float a1 = (s & 1) ? red[3] : red[2];
    float a2 = (s & 1) ? red[5] : red[4];
    float a3 = (s & 1) ? red[7] : red[6];
    float a4 = (s & 1) ? red[9] : red[8];
    float a5 = (s & 1) ? red[11] : red[10];
    float a6 = (s & 1) ? red[13] : red[12];
    float a7 = (s & 1) ? red[15] : red[14];
    float b0 = (s & 2) ? a1 : a0;
    float b1 = (s & 2) ? a3 : a2;
    float b2 = (s & 2) ? a5 : a4;
    float b3 = (s & 2) ? a7 : a6;
    float c0 = (s & 4) ? b1 : b0;
    float c1 = (s & 4) ? b3 : b2;
    float val = (s & 8) ? c1 : c0;
    int pos_l = (s >> 2) * 16 + g4 * 4 + (s & 3);
    int n = ch;  // 0..63, bijective over (w,c)
    *(bf16*)(smem + POOL_OFF + pos_l * 128 + ((n ^ ((pos_l & 7) << 3)) * 2)) =
        __float2bfloat16(val);
  }

  // ---- join: pooled written -> stage MmB into Mlds ----
  __syncthreads();
#pragma unroll
  for (int it = 0; it < 4; it++) {
    int P = it * 512 + tid;
    int row = P >> 3, u = P & 7;
    gload16((void*)(smem + MLDS_OFF + (it * 512 + w * 64) * 16),
            (const char*)MmBg + row * 128 + ((u ^ (row & 7)) << 4));
  }
  asm volatile("s_waitcnt vmcnt(0)" ::: "memory");
  __syncthreads();

  // ================= out = xres(LDS) + pooled @ MmB + bo (NT store) =================
  {
    char* Mlds = smem + MLDS_OFF;  // [256 o2][64 n], swizzled
    char* Plds = smem + POOL_OFF;  // [64 pos][64 n], swizzled
    const float* xres = (const float*)(smem + XRES_OFF);
    f32x4 oacc[2][4] = {};
#pragma unroll
    for (int kt = 0; kt < 2; kt++) {
      bf16x8 pf[4];
#pragma unroll
      for (int nfp = 0; nfp < 4; nfp++) {
        int prow = nfp * 16 + s;
        pf[nfp] = *(const bf16x8*)(Plds + prow * 128 + (((kt * 4 + g4) ^ (prow & 7)) << 4));
      }
#pragma unroll
      for (int mfo = 0; mfo < 2; mfo++) {
        int mrow = w * 32 + mfo * 16 + s;
        bf16x8 mfr = *(const bf16x8*)(Mlds + mrow * 128 + (((kt * 4 + g4) ^ (mrow & 7)) << 4));
#pragma unroll
        for (int nfp = 0; nfp < 4; nfp++)
          oacc[mfo][nfp] =
              __builtin_amdgcn_mfma_f32_16x16x32_bf16(mfr, pf[nfp], oacc[mfo][nfp], 0, 0, 0);
      }
    }
#pragma unroll
    for (int mfo = 0; mfo < 2; mfo++)
#pragma unroll
      for (int r = 0; r < 4; r++) {
        int o2 = w * 32 + mfo * 16 + g4 * 4 + r;
        float bov = bo[o2];
        float* orow = out + ((size_t)(bb * CDIM + o2) * LDIM) + l0;
#pragma unroll
        for (int nfp = 0; nfp < 4; nfp++) {
          int p = nfp * 16 + s;
          float xv = xres[o2 * 68 + p];
          __builtin_nontemporal_store(xv + oacc[mfo][nfp][r] + bov, orow + p);
        }
      }
  }
}

extern "C" void kernel_launch(void* const* d_in, const int* in_sizes, int n_in,
                              void* d_out, int out_size, void* d_ws, size_t ws_size,
                              hipStream_t stream) {
  (void)in_sizes; (void)n_in; (void)out_size; (void)ws_size;
  const float* x = (const float*)d_in[0];
  const float* Wq = (const float*)d_in[1];
  const float* bq = (const float*)d_in[2];
  const float* Wk = (const float*)d_in[3];
  const float* bk = (const float*)d_in[4];
  const float* v = (const float*)d_in[5];
  const float* Wo = (const float*)d_in[6];
  const float* bo = (const float*)d_in[7];
  float* out = (float*)d_out;

  char* ws = (char*)d_ws;
  bf16* Wqt = (bf16*)ws;                   // 524,288 (fragment-order tiles)
  bf16* Wkt = (bf16*)(ws + 524288);        // 524,288
  bf16* MmBg = (bf16*)(ws + 1048576);      // 32,768  (end 1,081,344)

  prep_kernel<<<512, 256, 0, stream>>>(Wq, Wk, v, Wo, Wqt, Wkt, MmBg);
  fused_kernel<<<256, 512, 0, stream>>>(x, Wqt, Wkt, bq, bk, MmBg, bo, out);
}

// Round 21
// 34.861 us; speedup vs baseline: 1.0256x; 1.0256x over previous
//
#include <hip/hip_runtime.h>
#include <hip/hip_bf16.h>
#include <stdint.h>

// B=4, C=256, H=W=64 -> L=4096, POS=16384; n_mem=64, sqrt_fin=16, scale=1/4.
// FINAL: R15 structure (best measured: 34.95 / 34.99 us across two runs).
// Session: 96.4 -> 35.0 us. Wins: fragment-order weight tiling (+14%),
// XCD chunk-phase rotation + LDS-resident residual (+6%).
using bf16 = __hip_bfloat16;
typedef __attribute__((ext_vector_type(8))) short bf16x8;
typedef __attribute__((ext_vector_type(4))) float f32x4;

#define CDIM 256
#define LDIM 4096

// LDS map (140 KiB), 64 pos/block, 256 blocks, 512 threads, 1 block/CU:
// xres @0      : [256 c][68 f32] padded residual tile (69632 B) -- persists to end
// Xs   @69632  : [64 p][256 k] bf16 swizzled (32 KB) -- dead after a_cache;
//                QSW [64p][16s][8w] bf16 overlays here after Q loop (16 KB)
// pooled @102400 : [64 p][64 n] bf16 swizzled (8 KB)
// Mlds @110592 : [256 o2][64 n] bf16 swizzled (32 KB), staged at join
#define XRES_OFF 0
#define XS_OFF 69632
#define POOL_OFF 102400
#define MLDS_OFF 110592

__device__ __forceinline__ void gload16(void* lds, const void* g) {
  auto* l3 = (__attribute__((address_space(3))) char*)(uintptr_t)lds;
  auto* g1 = (const __attribute__((address_space(1))) char*)(uintptr_t)g;
  __builtin_amdgcn_global_load_lds((const __attribute__((address_space(1))) void*)g1,
                                   (__attribute__((address_space(3))) void*)l3, 16, 0, 0);
}

template <int CTRL>
__device__ __forceinline__ float dpp_add(float v) {
  int p = __builtin_amdgcn_update_dpp(0, __float_as_int(v), CTRL, 0xf, 0xf, true);
  return v + __int_as_float(p);
}

__device__ __forceinline__ float b2f(short h) {
  return __uint_as_float(((uint32_t)(uint16_t)h) << 16);
}

// ---------- prep: weights -> bf16 FRAGMENT-ORDER tiles + MmB ----------
__global__ void prep_kernel(const float* __restrict__ Wq, const float* __restrict__ Wk,
                            const float* __restrict__ v, const float* __restrict__ Wo,
                            bf16* __restrict__ Wqt, bf16* __restrict__ Wkt,
                            bf16* __restrict__ MmBg) {
  int bid = blockIdx.x, t = threadIdx.x;
  if (bid < 256) {
    const float* src = (bid < 128) ? Wq : Wk;
    bf16* dst = (bid < 128) ? Wqt : Wkt;
    int f = (bid & 127) * 256 + t;  // 0..32767
    int l = f & 63, kt = (f >> 6) & 7, c2 = f >> 9;
    int row = c2 * 16 + (l & 15);
    int col0 = kt * 32 + (l >> 4) * 8;
    const float* sp = src + row * CDIM + col0;
    float4 fa = *(const float4*)sp;
    float4 fb = *(const float4*)(sp + 4);
    bf16 hv[8];
    hv[0] = __float2bfloat16(fa.x); hv[1] = __float2bfloat16(fa.y);
    hv[2] = __float2bfloat16(fa.z); hv[3] = __float2bfloat16(fa.w);
    hv[4] = __float2bfloat16(fb.x); hv[5] = __float2bfloat16(fb.y);
    hv[6] = __float2bfloat16(fb.z); hv[7] = __float2bfloat16(fb.w);
    *(uint4*)((char*)dst + (size_t)f * 16) = *(const uint4*)hv;
  } else {
    __shared__ float red[256];
    int o = bid - 256;
    int n = t >> 2, cg = t & 3;
    const float* vr = v + n * CDIM + cg * 64;
    const float* wr = Wo + o * CDIM + cg * 64;
    float a = 0.f;
    for (int c = 0; c < 64; c++) a += vr[c] * wr[c];
    red[t] = a;
    __syncthreads();
    if (t < 64)
      MmBg[o * 64 + t] =
          __float2bfloat16(red[t * 4] + red[t * 4 + 1] + red[t * 4 + 2] + red[t * 4 + 3]);
  }
}

__global__ __launch_bounds__(512, 1) void fused_kernel(
    const float* __restrict__ x, const bf16* __restrict__ Wqt, const bf16* __restrict__ Wkt,
    const float* __restrict__ bq, const float* __restrict__ bk,
    const bf16* __restrict__ MmBg, const float* __restrict__ bo, float* __restrict__ out) {
  __shared__ __align__(16) char smem[143360];
  const int tid = threadIdx.x;
  const int w = tid >> 6, lane = tid & 63;
  const int s = lane & 15, g4 = lane >> 4;
  const int pos0 = blockIdx.x * 64;
  const int bb = pos0 >> 12, l0 = pos0 & (LDIM - 1);
  // chunk-phase rotation: same-XCD blocks (bid%8 fixed) get different phases
  const int R = (blockIdx.x >> 3) & 7;
  const int wr = (w + R) & 7;

  // ---- bias hoist, indexed by ITERATION (iteration c handles chunk wr*8+((c+R)&7)) ----
  float bqr[8], bkr[8];
#pragma unroll
  for (int c = 0; c < 8; c++) {
    int ch = wr * 8 + ((c + R) & 7);
    bqr[c] = bq[ch * 16 + s];
    bkr[c] = bk[ch * 16 + s];
  }

  // ---- X stage: x [C][L] f32 -> Xs bf16 swizzled + xres f32 padded; NT loads ----
#pragma unroll
  for (int j = 0; j < 8; j++) {
    int slot = j * 512 + tid;  // 4096 float4 slots = 256 k x 16 (p/4)
    int k = slot >> 4, p0 = (slot & 15) * 4;
    f32x4 f = __builtin_nontemporal_load(
        (const f32x4*)(x + ((size_t)bb * CDIM + k) * LDIM + l0 + p0));
    *(f32x4*)(smem + XRES_OFF + (size_t)(k * 68 + p0) * 4) = f;  // residual copy
#pragma unroll
    for (int jj = 0; jj < 4; jj++) {
      int p = p0 + jj;
      *(bf16*)(smem + XS_OFF + p * 512 + (((k >> 3) ^ (p & 7)) << 4) + (k & 7) * 2) =
          __float2bfloat16(f[jj]);
    }
  }
  __syncthreads();

  // ---- A fragments -> registers/AGPRs: 32 x bf16x8 ----
  bf16x8 a_cache[4][8];
#pragma unroll
  for (int mf = 0; mf < 4; mf++) {
    int arow = mf * 16 + s;
#pragma unroll
    for (int kt = 0; kt < 8; kt++)
      a_cache[mf][kt] =
          *(const bf16x8*)(smem + XS_OFF + arow * 512 + (((kt * 4 + g4) ^ (arow & 7)) << 4));
  }

  // ================= Q projection: 8 chunks (rotated), weights -> VGPR =================
  float qacc[4][4] = {};
#pragma unroll 1
  for (int c = 0; c < 8; c++) {
    int ch = wr * 8 + ((c + R) & 7);
    const char* base = (const char*)Wqt + (size_t)ch * 8192 + lane * 16;
    bf16x8 wf[8];
#pragma unroll
    for (int kt = 0; kt < 8; kt++) wf[kt] = *(const bf16x8*)(base + kt * 1024);
    f32x4 acc[4] = {};
    __builtin_amdgcn_s_setprio(1);
#pragma unroll
    for (int kt = 0; kt < 8; kt++)
#pragma unroll
      for (int mf = 0; mf < 4; mf++)
        acc[mf] = __builtin_amdgcn_mfma_f32_16x16x32_bf16(a_cache[mf][kt], wf[kt], acc[mf], 0, 0, 0);
    __builtin_amdgcn_s_setprio(0);
#pragma unroll
    for (int mf = 0; mf < 4; mf++)
#pragma unroll
      for (int r = 0; r < 4; r++) qacc[mf][r] += fmaxf(acc[mf][r] + bqr[c], 0.f);
  }

  // ---- merge qsum across 8 waves via bf16 LDS (QSW overlays dead Xs) ----
#pragma unroll
  for (int mf = 0; mf < 4; mf++)
#pragma unroll
    for (int r = 0; r < 4; r++) {
      int pos_l = mf * 16 + g4 * 4 + r;
      *(bf16*)(smem + XS_OFF + ((pos_l * 16 + s) * 8 + w) * 2) = __float2bfloat16(qacc[mf][r]);
    }
  __syncthreads();
  float qreg[4][4];
#pragma unroll
  for (int mf = 0; mf < 4; mf++)
#pragma unroll
    for (int r = 0; r < 4; r++) {
      int pos_l = mf * 16 + g4 * 4 + r;
      bf16x8 vv = *(const bf16x8*)(smem + XS_OFF + (pos_l * 16 + s) * 16);
      float sum = 0.f;
#pragma unroll
      for (int j = 0; j < 8; j++) sum += b2f(vv[j]);
      qreg[mf][r] = 0.00390625f * sum;  // (1/4)/64
    }

  // ================= K projection: 8 chunks (rotated) + DPP s-reduce -> pooled =================
#pragma unroll 1
  for (int c = 0; c < 8; c++) {
    int ch = wr * 8 + ((c + R) & 7);
    const char* base = (const char*)Wkt + (size_t)ch * 8192 + lane * 16;
    bf16x8 wf[8];
#pragma unroll
    for (int kt = 0; kt < 8; kt++) wf[kt] = *(const bf16x8*)(base + kt * 1024);
    f32x4 acc[4] = {};
    __builtin_amdgcn_s_setprio(1);
#pragma unroll
    for (int kt = 0; kt < 8; kt++)
#pragma unroll
      for (int mf = 0; mf < 4; mf++)
        acc[mf] = __builtin_amdgcn_mfma_f32_16x16x32_bf16(a_cache[mf][kt], wf[kt], acc[mf], 0, 0, 0);
    __builtin_amdgcn_s_setprio(0);
    float red[16];
#pragma unroll
    for (int mf = 0; mf < 4; mf++)
#pragma unroll
      for (int r = 0; r < 4; r++) {
        float tt = qreg[mf][r] * fmaxf(acc[mf][r] + bkr[c], 0.f);
        tt = dpp_add<0x128>(tt);  // row_ror:8
        tt = dpp_add<0x124>(tt);  // row_ror:4
        tt = dpp_add<0x122>(tt);  // row_ror:2
        tt = dpp_add<0x121>(tt);  // row_ror:1
        red[mf * 4 + r] = tt;     // sum over 16 s-lanes, in all lanes
      }
    float a0 = (s & 1) ? red[1] : red[0];
    float a1 = (s & 1) ? red[3] : red[2];
    float a2 = (s & 1) ? red[5] : red[4];
    float a3 = (s & 1) ? red[7] : red[6];
    float a4 = (s & 1) ? red[9] : red[8];
    float a5 = (s & 1) ? red[11] : red[10];
    float a6 = (s & 1) ? red[13] : red[12];
    float a7 = (s & 1) ? red[15] : red[14];
    float b0 = (s & 2) ? a1 : a0;
    float b1 = (s & 2) ? a3 : a2;
    float b2 = (s & 2) ? a5 : a4;
    float b3 = (s & 2) ? a7 : a6;
    float c0 = (s & 4) ? b1 : b0;
    float c1 = (s & 4) ? b3 : b2;
    float val = (s & 8) ? c1 : c0;
    int pos_l = (s >> 2) * 16 + g4 * 4 + (s & 3);
    int n = ch;  // 0..63, bijective over (w,c)
    *(bf16*)(smem + POOL_OFF + pos_l * 128 + ((n ^ ((pos_l & 7) << 3)) * 2)) =
        __float2bfloat16(val);
  }

  // ---- join: pooled written -> stage MmB into Mlds ----
  __syncthreads();
#pragma unroll
  for (int it = 0; it < 4; it++) {
    int P = it * 512 + tid;
    int row = P >> 3, u = P & 7;
    gload16((void*)(smem + MLDS_OFF + (it * 512 + w * 64) * 16),
            (const char*)MmBg + row * 128 + ((u ^ (row & 7)) << 4));
  }
  asm volatile("s_waitcnt vmcnt(0)" ::: "memory");
  __syncthreads();

  // ================= out = xres(LDS) + pooled @ MmB + bo (NT store) =================
  {
    char* Mlds = smem + MLDS_OFF;  // [256 o2][64 n], swizzled
    char* Plds = smem + POOL_OFF;  // [64 pos][64 n], swizzled
    const float* xres = (const float*)(smem + XRES_OFF);
    f32x4 oacc[2][4] = {};
#pragma unroll
    for (int kt = 0; kt < 2; kt++) {
      bf16x8 pf[4];
#pragma unroll
      for (int nfp = 0; nfp < 4; nfp++) {
        int prow = nfp * 16 + s;
        pf[nfp] = *(const bf16x8*)(Plds + prow * 128 + (((kt * 4 + g4) ^ (prow & 7)) << 4));
      }
#pragma unroll
      for (int mfo = 0; mfo < 2; mfo++) {
        int mrow = w * 32 + mfo * 16 + s;
        bf16x8 mfr = *(const bf16x8*)(Mlds + mrow * 128 + (((kt * 4 + g4) ^ (mrow & 7)) << 4));
#pragma unroll
        for (int nfp = 0; nfp < 4; nfp++)
          oacc[mfo][nfp] =
              __builtin_amdgcn_mfma_f32_16x16x32_bf16(mfr, pf[nfp], oacc[mfo][nfp], 0, 0, 0);
      }
    }
#pragma unroll
    for (int mfo = 0; mfo < 2; mfo++)
#pragma unroll
      for (int r = 0; r < 4; r++) {
        int o2 = w * 32 + mfo * 16 + g4 * 4 + r;
        float bov = bo[o2];
        float* orow = out + ((size_t)(bb * CDIM + o2) * LDIM) + l0;
#pragma unroll
        for (int nfp = 0; nfp < 4; nfp++) {
          int p = nfp * 16 + s;
          float xv = xres[o2 * 68 + p];
          __builtin_nontemporal_store(xv + oacc[mfo][nfp][r] + bov, orow + p);
        }
      }
  }
}

extern "C" void kernel_launch(void* const* d_in, const int* in_sizes, int n_in,
                              void* d_out, int out_size, void* d_ws, size_t ws_size,
                              hipStream_t stream) {
  (void)in_sizes; (void)n_in; (void)out_size; (void)ws_size;
  const float* x = (const float*)d_in[0];
  const float* Wq = (const float*)d_in[1];
  const float* bq = (const float*)d_in[2];
  const float* Wk = (const float*)d_in[3];
  const float* bk = (const float*)d_in[4];
  const float* v = (const float*)d_in[5];
  const float* Wo = (const float*)d_in[6];
  const float* bo = (const float*)d_in[7];
  float* out = (float*)d_out;

  char* ws = (char*)d_ws;
  bf16* Wqt = (bf16*)ws;                   // 524,288 (fragment-order tiles)
  bf16* Wkt = (bf16*)(ws + 524288);        // 524,288
  bf16* MmBg = (bf16*)(ws + 1048576);      // 32,768  (end 1,081,344)

  prep_kernel<<<512, 256, 0, stream>>>(Wq, Wk, v, Wo, Wqt, Wkt, MmBg);
  fused_kernel<<<256, 512, 0, stream>>>(x, Wqt, Wkt, bq, bk, MmBg, bo, out);
}